// Round 9
// baseline (644.241 us; speedup 1.0000x reference)
//
#include <hip/hip_runtime.h>

#define N_NODES 100000
#define N_EDGES 1200000
#define DIM     64
#define N_LAYERS 3
#define N_GRAPHS 512
#define OUTD    192   // 3 * 64, concat layout
#define BN_EPS  1e-5f

#define NPB 64            // nodes per block in layer_kernel
#define LDS_PITCH 65      // +1 pad -> 2-way bank aliasing only (free)
#define NLBLK ((N_NODES + NPB - 1) / NPB)                 // 1563

// ---- single-kernel binning geometry ----
#define BSHIFT 9
#define BUCK_NODES (1 << BSHIFT)                          // 512 nodes / bucket
#define NBUK ((N_NODES + BUCK_NODES - 1) / BUCK_NODES)    // 196
#define NBLK2 256                                         // bin_all grid (1/CU, co-resident)
#define EPB2 ((N_EDGES + NBLK2 - 1) / NBLK2)              // 4688 edges/chunk

__device__ __forceinline__ unsigned short f2bf(float f) {
    unsigned u = __float_as_uint(f);
    return (unsigned short)((u + 0x7FFFu + ((u >> 16) & 1u)) >> 16);   // RNE
}
__device__ __forceinline__ float bf2f(unsigned short h) {
    return __uint_as_float(((unsigned)h) << 16);
}

// Software grid barrier (generation-based). SAFE ONLY because bin_all's 256
// blocks x 256 threads x 3KB LDS are all co-resident (1 block/CU on 256 CUs).
// bc[0]=arrival count, bc[1]=generation; both zeroed by transpose_w each run.
__device__ __forceinline__ void gbar(int* bc) {
    __syncthreads();
    if (threadIdx.x == 0) {
        int g = __hip_atomic_load(&bc[1], __ATOMIC_RELAXED, __HIP_MEMORY_SCOPE_AGENT);
        __threadfence();
        int a = __hip_atomic_fetch_add(&bc[0], 1, __ATOMIC_ACQ_REL, __HIP_MEMORY_SCOPE_AGENT);
        if (a == NBLK2 - 1) {
            __hip_atomic_store(&bc[0], 0, __ATOMIC_RELAXED, __HIP_MEMORY_SCOPE_AGENT);
            __hip_atomic_store(&bc[1], g + 1, __ATOMIC_RELEASE, __HIP_MEMORY_SCOPE_AGENT);
        } else {
            while (__hip_atomic_load(&bc[1], __ATOMIC_ACQUIRE, __HIP_MEMORY_SCOPE_AGENT) <= g) {
                __builtin_amdgcn_s_sleep(2);
            }
        }
        __threadfence();
    }
    __syncthreads();
}

// ---------------------------------------------------------------------------
// Transpose W1/W2; identity affine; zero barrier counters.
__global__ void transpose_w(const float* __restrict__ W1, const float* __restrict__ W2,
                            float* __restrict__ W1T, float* __restrict__ W2T,
                            float* __restrict__ idaff, int* __restrict__ barcnt) {
    int idx = blockIdx.x * blockDim.x + threadIdx.x;  // L*64*64
    if (idx < 128) idaff[idx] = (idx < 64) ? 1.0f : 0.0f;
    if (idx < 2) barcnt[idx] = 0;
    if (idx >= N_LAYERS * DIM * DIM) return;
    int l = idx >> 12;
    int r = idx & 4095;
    int j = r >> 6;
    int k = r & 63;
    int dstp = (l << 12) + k * DIM + j;
    W1T[dstp] = W1[idx];
    W2T[dstp] = W2[idx];
}

// ---------------------------------------------------------------------------
// ALL of binning in ONE kernel (R9: 5 dispatches + ~60us of gaps -> 1):
// phase1 per-chunk bucket hist -> phase2 per-bucket column scan (bases +
// colsum) -> phase3 scatter into bucket-partitioned pp -> phase4 per-bucket
// counting sort -> CSR (seg, pe). Grid barriers between phases.
__global__ void __launch_bounds__(256) bin_all(
        const int* __restrict__ src, const int* __restrict__ dst,
        const float* __restrict__ ew,
        int* __restrict__ hist,    // [NBLK2][NBUK]
        int* __restrict__ pbase,   // [NBLK2][NBUK] (chunk-local, no bucket base)
        int* __restrict__ colsum,  // [NBUK]
        int2* __restrict__ pp, int* __restrict__ seg, int2* __restrict__ pe,
        int* __restrict__ barcnt) {
    __shared__ int sA[512];
    __shared__ int sB[256];
    __shared__ int sC[256];
    int k = blockIdx.x, t = threadIdx.x;
    int e0 = k * EPB2;
    int e1 = e0 + EPB2; if (e1 > N_EDGES) e1 = N_EDGES;

    // ---- phase 1: per-chunk histogram (LDS atomics only) ----
    if (t < NBUK) sB[t] = 0;
    __syncthreads();
    for (int e = e0 + t; e < e1; e += 256) atomicAdd(&sB[dst[e] >> BSHIFT], 1);
    __syncthreads();
    if (t < NBUK) hist[k * NBUK + t] = sB[t];
    gbar(barcnt);

    // ---- phase 2: bucket k<NBUK scans its column over 256 chunks ----
    if (k < NBUK) {
        int v = hist[t * NBUK + k];
        sA[t] = v;
        __syncthreads();
        for (int o = 1; o < 256; o <<= 1) {
            int add = (t >= o) ? sA[t - o] : 0;
            __syncthreads();
            sA[t] += add;
            __syncthreads();
        }
        pbase[t * NBUK + k] = sA[t] - v;      // exclusive within bucket
        if (t == 255) colsum[k] = sA[255];
    }
    gbar(barcnt);

    // ---- phase 3: every block computes bucket-start prefix, scatters ----
    {
        int cs = (t < NBUK) ? colsum[t] : 0;
        sA[t] = cs;
        __syncthreads();
        for (int o = 1; o < 256; o <<= 1) {
            int add = (t >= o) ? sA[t - o] : 0;
            __syncthreads();
            sA[t] += add;
            __syncthreads();
        }
        if (t < NBUK) sC[t] = sA[t] - cs + pbase[k * NBUK + t];   // cursors
        __syncthreads();
        for (int e = e0 + t; e < e1; e += 256) {
            int d = dst[e];
            int bk = d >> BSHIFT;
            int pos = atomicAdd(&sC[bk], 1);
            pp[pos] = make_int2(src[e] | ((d & (BUCK_NODES - 1)) << 17),
                                __float_as_int(ew[e]));
        }
    }
    gbar(barcnt);

    // ---- phase 4: bucket k<NBUK counting sort -> CSR ----
    if (k < NBUK) {
        int cs = (t < NBUK) ? colsum[t] : 0;
        sB[t] = cs;
        __syncthreads();
        for (int o = 1; o < 256; o <<= 1) {
            int add = (t >= o) ? sB[t - o] : 0;
            __syncthreads();
            sB[t] += add;
            __syncthreads();
        }
        int eend = sB[k];
        int ebeg = eend - colsum[k];
        sA[t] = 0; sA[t + 256] = 0;
        __syncthreads();
        for (int e = ebeg + t; e < eend; e += 256)
            atomicAdd(&sA[pp[e].x >> 17], 1);
        __syncthreads();
        int c0 = sA[2 * t], c1 = sA[2 * t + 1];
        int ps = c0 + c1;
        sC[t] = ps;
        __syncthreads();
        for (int o = 1; o < 256; o <<= 1) {
            int add = (t >= o) ? sC[t - o] : 0;
            __syncthreads();
            sC[t] += add;
            __syncthreads();
        }
        int excl = sC[t] - ps;
        int o0 = ebeg + excl;
        int o1 = o0 + c0;
        int n0 = (k << BSHIFT) + 2 * t;
        if (n0 < N_NODES) seg[n0] = o0;
        if (n0 + 1 < N_NODES) seg[n0 + 1] = o1;
        __syncthreads();              // c0/c1 reads retired
        sA[2 * t] = o0;               // reuse as global cursors
        sA[2 * t + 1] = o1;
        __syncthreads();
        for (int e = ebeg + t; e < eend; e += 256) {
            int2 p = pp[e];
            int pos = atomicAdd(&sA[p.x >> 17], 1);
            pe[pos] = make_int2(p.x & 0x1FFFF, p.y);   // plain (src, w)
        }
        if (k == 0 && t == 0) seg[N_NODES] = N_EDGES;
    }
}

// ---------------------------------------------------------------------------
// Fused layer (R7 structure, best measured 87.6us): quarter-wave float4
// gather; BF16IN selects neighbor-row source (layer 0: f32 from x_in,
// layers 1-2: bf16 shadow). Self term always f32. Epilogue writes f32 xs
// and (wr16) bf16 shadow for the next layer.
template <int BF16IN>
__global__ void __launch_bounds__(256) layer_kernel(
    const float* __restrict__ x_in, int xstride,          // f32 rows
    const unsigned short* __restrict__ x16in,             // bf16 neighbor rows
    unsigned short* __restrict__ x16out, int wr16,
    const int* __restrict__ seg,     // CSR offsets (N+1)
    const int2* __restrict__ pe,     // (src, w)
    const float* __restrict__ affine /* [128]: scale|shift of input */,
    const float* __restrict__ W1T, const float* __restrict__ b1,
    const float* __restrict__ W2T, const float* __restrict__ b2,
    float* __restrict__ out /* xs base + layer*64, row stride OUTD */,
    float* __restrict__ pstat /* [NLBLK][128]: sum|sumsq partials */) {
    __shared__ float lds[NPB * LDS_PITCH];
    int t = threadIdx.x;
    int lane = t & 63;
    int wid = __builtin_amdgcn_readfirstlane(t >> 6);   // wave id 0..3, SGPR
    int nbase = blockIdx.x * NPB;

    int slot = lane >> 4;            // 0..3: which edge of a 4-group
    int col  = lane & 15;            // which float4 of the row
    const float4* aff4 = (const float4*)affine;
    float4 sc4 = aff4[col];          // scale for cols 4c..4c+3
    float4 sh4 = aff4[16 + col];     // shift

    // ---- Phase 1: gather (16 nodes per wave, node id wave-uniform) ----
    for (int nn = 0; nn < 16; ++nn) {
        int nl = wid * 16 + nn;
        int n = nbase + nl;
        float ax = 0.f, ay = 0.f, az = 0.f, aw = 0.f, wsa = 0.f;
        float bx = 0.f, by = 0.f, bz = 0.f, bw = 0.f, wsb = 0.f;
        if (n < N_NODES) {
            int beg = seg[n];
            int end = seg[n + 1];
#define GBODY(EI, X, Y, Z, W, WS)                                              \
            if ((EI) < end) {                                                  \
                int2 p = pe[EI];                                               \
                float w = __int_as_float(p.y);                                 \
                float vx, vy, vz, vw;                                          \
                if (BF16IN) {                                                  \
                    ushort4 hv =                                               \
                        ((const ushort4*)(x16in + (size_t)p.x * DIM))[col];    \
                    vx = bf2f(hv.x); vy = bf2f(hv.y);                          \
                    vz = bf2f(hv.z); vw = bf2f(hv.w);                          \
                } else {                                                       \
                    float4 fv =                                                \
                        ((const float4*)(x_in + (size_t)p.x * xstride))[col];  \
                    vx = fv.x; vy = fv.y; vz = fv.z; vw = fv.w;                \
                }                                                              \
                X = fmaf(w, vx, X); Y = fmaf(w, vy, Y);                        \
                Z = fmaf(w, vz, Z); W = fmaf(w, vw, W);                        \
                WS += w;                                                       \
            }
            for (int e = beg; e < end; e += 16) {
                int e0 = e + slot;
                GBODY(e0,      ax, ay, az, aw, wsa)
                GBODY(e0 + 4,  bx, by, bz, bw, wsb)
                GBODY(e0 + 8,  ax, ay, az, aw, wsa)
                GBODY(e0 + 12, bx, by, bz, bw, wsb)
            }
#undef GBODY
        }
        float sx = ax + bx, sy = ay + by, sz = az + bz, sw = aw + bw;
        float ws = wsa + wsb;
        // reduce across the 4 slots (lane bits 4,5); all lanes get totals
        sx += __shfl_xor(sx, 16); sy += __shfl_xor(sy, 16);
        sz += __shfl_xor(sz, 16); sw += __shfl_xor(sw, 16);
        ws += __shfl_xor(ws, 16);
        sx += __shfl_xor(sx, 32); sy += __shfl_xor(sy, 32);
        sz += __shfl_xor(sz, 32); sw += __shfl_xor(sw, 32);
        ws += __shfl_xor(ws, 32);
        if (lane < 16) {
            float r0 = 0.f, r1 = 0.f, r2 = 0.f, r3 = 0.f;
            if (n < N_NODES) {
                const float4* xr =
                    (const float4*)(x_in + (size_t)n * xstride) + col;
                float4 s = *xr;                       // self term, f32
                float shw = 1.0f + ws;
                r0 = fmaf(sc4.x, sx + s.x, sh4.x * shw);
                r1 = fmaf(sc4.y, sy + s.y, sh4.y * shw);
                r2 = fmaf(sc4.z, sz + s.z, sh4.z * shw);
                r3 = fmaf(sc4.w, sw + s.w, sh4.w * shw);
            }
            int lb = nl * LDS_PITCH + col * 4;
            lds[lb] = r0; lds[lb + 1] = r1; lds[lb + 2] = r2; lds[lb + 3] = r3;
        }
    }
    __syncthreads();

    // ---- Stage 1 GEMM: hidden = relu(xin @ W1^T + b1) ----
    float h[16];
#pragma unroll
    for (int jj = 0; jj < 16; ++jj) h[jj] = b1[wid * 16 + jj];
#pragma unroll 4
    for (int k = 0; k < DIM; ++k) {
        float xv = lds[lane * LDS_PITCH + k];
        const float* wr = W1T + k * DIM + wid * 16;   // uniform -> s_load
#pragma unroll
        for (int jj = 0; jj < 16; ++jj) h[jj] = fmaf(xv, wr[jj], h[jj]);
    }
#pragma unroll
    for (int jj = 0; jj < 16; ++jj) h[jj] = fmaxf(h[jj], 0.0f);
    __syncthreads();          // all lds (xin) reads done
#pragma unroll
    for (int jj = 0; jj < 16; ++jj) lds[lane * LDS_PITCH + wid * 16 + jj] = h[jj];
    __syncthreads();

    // ---- Stage 2 GEMM: o = relu(hidden @ W2^T + b2) ----
    float o[16];
#pragma unroll
    for (int jj = 0; jj < 16; ++jj) o[jj] = b2[wid * 16 + jj];
#pragma unroll 4
    for (int k = 0; k < DIM; ++k) {
        float hv = lds[lane * LDS_PITCH + k];
        const float* wr = W2T + k * DIM + wid * 16;
#pragma unroll
        for (int jj = 0; jj < 16; ++jj) o[jj] = fmaf(hv, wr[jj], o[jj]);
    }
    int n = nbase + lane;
    bool valid = (n < N_NODES);
#pragma unroll
    for (int jj = 0; jj < 16; ++jj) o[jj] = fmaxf(o[jj], 0.0f);
    if (valid) {
        float* orow = out + (size_t)n * OUTD + wid * 16;
#pragma unroll
        for (int jj = 0; jj < 16; jj += 4) {
            *(float4*)(orow + jj) = make_float4(o[jj], o[jj + 1], o[jj + 2], o[jj + 3]);
        }
        if (wr16) {
            unsigned short* hrow = x16out + (size_t)n * DIM + wid * 16;
#pragma unroll
            for (int jj = 0; jj < 16; jj += 4) {
                ushort4 hq;
                hq.x = f2bf(o[jj]);     hq.y = f2bf(o[jj + 1]);
                hq.z = f2bf(o[jj + 2]); hq.w = f2bf(o[jj + 3]);
                *(ushort4*)(hrow + jj) = hq;
            }
        }
    }

    // ---- BN stat partials: butterfly over 64 lanes; wave wid owns dims
    // [wid*16, wid*16+16). Non-atomic coalesced per-block store.
    float my_s = 0.0f, my_q = 0.0f;
#pragma unroll
    for (int jj = 0; jj < 16; ++jj) {
        float v = valid ? o[jj] : 0.0f;
        float vs = v, vq = v * v;
#pragma unroll
        for (int m = 1; m < 64; m <<= 1) {
            vs += __shfl_xor(vs, m);
            vq += __shfl_xor(vq, m);
        }
        if (lane == jj) { my_s = vs; my_q = vq; }
    }
    if (lane < 16) {
        size_t base = (size_t)blockIdx.x * 128 + wid * 16 + lane;
        pstat[base] = my_s;
        pstat[base + 64] = my_q;
    }
}

// ---------------------------------------------------------------------------
// Reduce per-block BN partials -> scale/shift; optionally zero pooled
// (folds the pooled memset's dispatch into the last reduce).
__global__ void __launch_bounds__(256) reduce_stats(
    const float* __restrict__ pstat,
    const float* __restrict__ gamma, const float* __restrict__ beta,
    float* __restrict__ ss /* [128]: scale|shift */,
    float* __restrict__ pooled, int zpool) {
    __shared__ double part[16][16];
    int b = blockIdx.x;            // 0..7
    int t = threadIdx.x;
    if (zpool) {
        for (int i = b * 256 + t; i < N_GRAPHS * OUTD; i += 8 * 256)
            pooled[i] = 0.0f;
    }
    int slot = t & 15;             // 0..7 -> sum(d), 8..15 -> sumsq(d)
    int g = t >> 4;                // group 0..15
    int d = b * 8 + (slot & 7);
    int off = (slot < 8) ? 0 : 64;
    double s = 0.0;
    for (int blk = g; blk < NLBLK; blk += 16)
        s += (double)pstat[(size_t)blk * 128 + off + d];
    part[g][slot] = s;
    __syncthreads();
    if (t < 16) {
        double x = 0.0;
#pragma unroll
        for (int k = 0; k < 16; ++k) x += part[k][t];
        part[0][t] = x;            // column t only -> no hazard
    }
    __syncthreads();
    if (t < 8) {
        int dd = b * 8 + t;
        double mu = part[0][t] / (double)N_NODES;
        double var = part[0][8 + t] / (double)N_NODES - mu * mu;
        float inv = (float)(1.0 / sqrt(var + (double)BN_EPS));
        float sc = gamma[dd] * inv;
        ss[dd] = sc;
        ss[64 + dd] = beta[dd] - (float)mu * sc;
    }
}

// ---------------------------------------------------------------------------
// Final pass: apply BN affine to xs IN PLACE (all 3 layers at once) and
// add-pool per graph. Grid (512 graphs, 4 parts), block 192.
__global__ void bn_pool(float* __restrict__ xs,
                        const int* __restrict__ batch,
                        const float* __restrict__ ss /* [3][128] */,
                        float* __restrict__ pooled) {
    int g = blockIdx.x;
    int part = blockIdx.y;   // 0..3
    int d = threadIdx.x;     // 0..191
    int l = d >> 6, dd = d & 63;
    float sc = ss[l * 128 + dd];
    float sh = ss[l * 128 + 64 + dd];
    int start, end;
    {
        int lo = 0, hi = N_NODES;
        while (lo < hi) { int m = (lo + hi) >> 1; if (batch[m] < g) lo = m + 1; else hi = m; }
        start = lo;
    }
    {
        int lo = start, hi = N_NODES;
        while (lo < hi) { int m = (lo + hi) >> 1; if (batch[m] <= g) lo = m + 1; else hi = m; }
        end = lo;
    }
    float acc = 0.0f;
    for (int n = start + part; n < end; n += 4) {
        float* p = xs + (size_t)n * OUTD + d;
        float v = fmaf(*p, sc, sh);
        *p = v;
        acc += v;
    }
    atomicAdd(&pooled[(size_t)g * OUTD + d], acc);
}

// ---------------------------------------------------------------------------
extern "C" void kernel_launch(void* const* d_in, const int* in_sizes, int n_in,
                              void* d_out, int out_size, void* d_ws, size_t ws_size,
                              hipStream_t stream) {
    const float* x0    = (const float*)d_in[0];
    const int*   ei    = (const int*)d_in[1];
    const float* ew    = (const float*)d_in[2];
    const int*   batch = (const int*)d_in[3];
    const float* W1    = (const float*)d_in[5];
    const float* b1    = (const float*)d_in[6];
    const float* W2    = (const float*)d_in[7];
    const float* b2    = (const float*)d_in[8];
    const float* gamma = (const float*)d_in[9];
    const float* beta  = (const float*)d_in[10];

    float* pooled = (float*)d_out;                      // [512, 192]
    float* xs     = pooled + (size_t)N_GRAPHS * OUTD;   // [100000, 192]

    const int* src = ei;
    const int* dst = ei + N_EDGES;

    // Workspace (~36.5 MB): head = persistent; tail union = {binning scratch}
    // overlapped with {x16 ping-pong} (pp/hist/pbase dead before layer 0
    // writes x16b; layer 0 reads f32 so needs no x16 input).
    int2*  pe     = (int2*)d_ws;                        // E  9.6 MB
    int*   seg    = (int*)(pe + N_EDGES);               // N+4
    int*   colsum = seg + N_NODES + 4;                  // NBUK+4
    int*   barcnt = colsum + NBUK + 4;                  // 2 (+pad)
    float* W1T    = (float*)(barcnt + 4);
    float* W2T    = W1T + N_LAYERS * DIM * DIM;
    float* idaff  = W2T + N_LAYERS * DIM * DIM;         // 128 floats
    float* ss     = idaff + 128;                        // 3*128 floats
    float* pstat  = ss + N_LAYERS * 128;                // NLBLK*128 floats
    // union region:
    char* uni = (char*)(pstat + (size_t)NLBLK * 128);
    int2*  pp     = (int2*)uni;                         // E (binning only)
    int*   hist   = (int*)(pp + N_EDGES);               // NBLK2*NBUK
    int*   pbase  = hist + (size_t)NBLK2 * NBUK;        // NBLK2*NBUK
    unsigned short* x16a = (unsigned short*)uni;        // N*64 bf16 (12.8 MB)
    unsigned short* x16b = x16a + (size_t)N_NODES * DIM;

    transpose_w<<<(N_LAYERS * DIM * DIM + 255) / 256, 256, 0, stream>>>(
        W1, W2, W1T, W2T, idaff, barcnt);

    // One-kernel binning (software grid barriers; 256 co-resident blocks).
    bin_all<<<NBLK2, 256, 0, stream>>>(src, dst, ew, hist, pbase, colsum,
                                       pp, seg, pe, barcnt);

    for (int i = 0; i < N_LAYERS; ++i) {
        const float* xin = (i == 0) ? x0 : (xs + (size_t)(i - 1) * DIM);
        int xstride = (i == 0) ? DIM : OUTD;
        const float* affine = (i == 0) ? idaff : (ss + (size_t)(i - 1) * 128);
        const unsigned short* x16in = (i == 1) ? x16b : x16a;
        unsigned short* x16out = (i == 0) ? x16b : x16a;
        int wr16 = (i < N_LAYERS - 1) ? 1 : 0;

        if (i == 0) {
            layer_kernel<0><<<NLBLK, 256, 0, stream>>>(
                xin, xstride, x16in, x16out, wr16, seg, pe, affine,
                W1T + (size_t)i * DIM * DIM, b1 + (size_t)i * DIM,
                W2T + (size_t)i * DIM * DIM, b2 + (size_t)i * DIM,
                xs + (size_t)i * DIM, pstat);
        } else {
            layer_kernel<1><<<NLBLK, 256, 0, stream>>>(
                xin, xstride, x16in, x16out, wr16, seg, pe, affine,
                W1T + (size_t)i * DIM * DIM, b1 + (size_t)i * DIM,
                W2T + (size_t)i * DIM * DIM, b2 + (size_t)i * DIM,
                xs + (size_t)i * DIM, pstat);
        }

        reduce_stats<<<8, 256, 0, stream>>>(
            pstat, gamma + (size_t)i * DIM, beta + (size_t)i * DIM,
            ss + (size_t)i * 128, pooled, (i == N_LAYERS - 1) ? 1 : 0);
    }

    dim3 pgrid(N_GRAPHS, 4);
    bn_pool<<<pgrid, OUTD, 0, stream>>>(xs, batch, ss, pooled);
}

// Round 10
// 528.127 us; speedup vs baseline: 1.2199x; 1.2199x over previous
//
#include <hip/hip_runtime.h>

#define N_NODES 100000
#define N_EDGES 1200000
#define DIM     64
#define N_LAYERS 3
#define N_GRAPHS 512
#define OUTD    192   // 3 * 64, concat layout
#define BN_EPS  1e-5f

#define NPB 64            // nodes per block in layer_kernel
#define LDS_PITCH 65      // +1 pad -> 2-way bank aliasing only (free)
#define NLBLK ((N_NODES + NPB - 1) / NPB)                 // 1563

// ---- two-level binning geometry ----
#define BSHIFT 9
#define BUCK_NODES (1 << BSHIFT)                          // 512 nodes / bucket
#define NBUK ((N_NODES + BUCK_NODES - 1) / BUCK_NODES)    // 196
#define EPB 4096                                          // edges per partition block
#define NPBLK ((N_EDGES + EPB - 1) / EPB)                 // 293

__device__ __forceinline__ unsigned short f2bf(float f) {
    unsigned u = __float_as_uint(f);
    return (unsigned short)((u + 0x7FFFu + ((u >> 16) & 1u)) >> 16);   // RNE
}
__device__ __forceinline__ float bf2f(unsigned short h) {
    return __uint_as_float(((unsigned)h) << 16);
}

// ---------------------------------------------------------------------------
// Transpose W1/W2; identity affine; zero the bucket-total array (folds the
// memset dispatch).
__global__ void transpose_w(const float* __restrict__ W1, const float* __restrict__ W2,
                            float* __restrict__ W1T, float* __restrict__ W2T,
                            float* __restrict__ idaff, int* __restrict__ tot) {
    int idx = blockIdx.x * blockDim.x + threadIdx.x;  // L*64*64
    if (idx < 128) idaff[idx] = (idx < 64) ? 1.0f : 0.0f;
    if (idx < NBUK + 4) tot[idx] = 0;
    if (idx >= N_LAYERS * DIM * DIM) return;
    int l = idx >> 12;
    int r = idx & 4095;
    int j = r >> 6;
    int k = r & 63;
    int dstp = (l << 12) + k * DIM + j;
    W1T[dstp] = W1[idx];
    W2T[dstp] = W2[idx];
}

// ---------------------------------------------------------------------------
// Phase A: per-block bucket histogram (LDS atomics) + global bucket totals
// (196 addresses x 293 adds each, spread over time -> negligible contention).
__global__ void __launch_bounds__(256) part_hist(const int* __restrict__ dst,
                                                 int* __restrict__ hist,
                                                 int* __restrict__ tot) {
    __shared__ int h[NBUK];
    int t = threadIdx.x;
    if (t < NBUK) h[t] = 0;
    __syncthreads();
    int base = blockIdx.x * EPB;
    for (int i = t; i < EPB; i += 256) {
        int e = base + i;
        if (e < N_EDGES) atomicAdd(&h[dst[e] >> BSHIFT], 1);
    }
    __syncthreads();
    if (t < NBUK) {
        int v = h[t];
        hist[blockIdx.x * NBUK + t] = v;
        if (v) atomicAdd(&tot[t], v);
    }
}

// ---------------------------------------------------------------------------
// Phase B: per-(block,bucket) bases. Block b inlines the 196-entry bucket
// prefix (replaces the scan196 dispatch), then scans hist column b.
__global__ void __launch_bounds__(256) base_fill(const int* __restrict__ hist,
                                                 const int* __restrict__ tot,
                                                 int* __restrict__ base) {
    __shared__ int c[512];
    __shared__ int ssum[256];
    __shared__ int btot[256];
    int b = blockIdx.x, t = threadIdx.x;
    // inline bucket-start prefix
    btot[t] = (t < NBUK) ? tot[t] : 0;
    __syncthreads();
    for (int o = 1; o < 256; o <<= 1) {
        int add = (t >= o) ? btot[t - o] : 0;
        __syncthreads();
        btot[t] += add;
        __syncthreads();
    }
    int bstart_b = (b == 0) ? 0 : btot[b - 1];   // exclusive start, uniform
    // column scan of hist[:, b]
    c[t] = (t < NPBLK) ? hist[t * NBUK + b] : 0;
    c[t + 256] = (t + 256 < NPBLK) ? hist[(t + 256) * NBUK + b] : 0;
    __syncthreads();
    int c0 = c[2 * t], c1 = c[2 * t + 1];
    int ps = c0 + c1;
    ssum[t] = ps;
    __syncthreads();
    int v = ps;
    for (int o = 1; o < 256; o <<= 1) {
        int add = (t >= o) ? ssum[t - o] : 0;
        __syncthreads();
        ssum[t] += add;
        __syncthreads();
    }
    int excl = ssum[t] - v + bstart_b;      // exclusive over pairs + bucket base
    if (2 * t < NPBLK)     base[(2 * t) * NBUK + b] = excl;
    if (2 * t + 1 < NPBLK) base[(2 * t + 1) * NBUK + b] = excl + c0;
}

// ---------------------------------------------------------------------------
// Phase C: scatter edges into bucket-partitioned order.
__global__ void __launch_bounds__(256) part_scatter(
        const int* __restrict__ src, const int* __restrict__ dst,
        const float* __restrict__ ew, const int* __restrict__ base,
        int2* __restrict__ pp) {
    __shared__ int cur[NBUK];
    int t = threadIdx.x;
    if (t < NBUK) cur[t] = base[blockIdx.x * NBUK + t];
    __syncthreads();
    int bb = blockIdx.x * EPB;
    for (int i = t; i < EPB; i += 256) {
        int e = bb + i;
        if (e < N_EDGES) {
            int d = dst[e];
            int bk = d >> BSHIFT;
            int pos = atomicAdd(&cur[bk], 1);
            int dl = d & (BUCK_NODES - 1);
            pp[pos] = make_int2(src[e] | (dl << 17), __float_as_int(ew[e]));
        }
    }
}

// ---------------------------------------------------------------------------
// Phase D: per-bucket counting sort -> CSR. Inlines the bucket prefix
// (replaces scan196's bstart). Writes confined to ~48KB L2-resident window.
__global__ void __launch_bounds__(256) csr_build(
        const int2* __restrict__ pp, const int* __restrict__ tot,
        int* __restrict__ seg, int2* __restrict__ pe) {
    __shared__ int cnt[BUCK_NODES];
    __shared__ int ssum[256];
    __shared__ int btot[256];
    int b = blockIdx.x, t = threadIdx.x;
    btot[t] = (t < NBUK) ? tot[t] : 0;
    __syncthreads();
    for (int o = 1; o < 256; o <<= 1) {
        int add = (t >= o) ? btot[t - o] : 0;
        __syncthreads();
        btot[t] += add;
        __syncthreads();
    }
    int eend = btot[b];                      // inclusive prefix, uniform
    int ebeg = (b == 0) ? 0 : btot[b - 1];
    cnt[t] = 0;
    cnt[t + 256] = 0;
    __syncthreads();
    for (int e = ebeg + t; e < eend; e += 256)
        atomicAdd(&cnt[pp[e].x >> 17], 1);
    __syncthreads();
    int c0 = cnt[2 * t], c1 = cnt[2 * t + 1];
    int ps = c0 + c1;
    ssum[t] = ps;
    __syncthreads();
    int v = ps;
    for (int o = 1; o < 256; o <<= 1) {
        int add = (t >= o) ? ssum[t - o] : 0;
        __syncthreads();
        ssum[t] += add;
        __syncthreads();
    }
    int excl = ssum[t] - v;           // exclusive over pairs
    int o0 = ebeg + excl;
    int o1 = o0 + c0;
    int n0 = (b << BSHIFT) + 2 * t;
    if (n0 < N_NODES) seg[n0] = o0;
    if (n0 + 1 < N_NODES) seg[n0 + 1] = o1;
    __syncthreads();                  // all cnt reads (c0,c1) retired
    cnt[2 * t] = o0;                  // reuse as cursors (global positions)
    cnt[2 * t + 1] = o1;
    __syncthreads();
    for (int e = ebeg + t; e < eend; e += 256) {
        int2 p = pp[e];
        int pos = atomicAdd(&cnt[p.x >> 17], 1);
        pe[pos] = make_int2(p.x & 0x1FFFF, p.y);   // plain (src, w)
    }
    if (b == 0 && t == 0) seg[N_NODES] = N_EDGES;
}

// ---------------------------------------------------------------------------
// Fused layer (R7 structure, best measured 87.6us): quarter-wave float4
// gather; BF16IN selects neighbor-row source (layer 0: f32 from x_in,
// layers 1-2: bf16 shadow). Self term always f32. Epilogue writes f32 xs
// and (wr16) bf16 shadow for the next layer.
template <int BF16IN>
__global__ void __launch_bounds__(256) layer_kernel(
    const float* __restrict__ x_in, int xstride,          // f32 rows
    const unsigned short* __restrict__ x16in,             // bf16 neighbor rows
    unsigned short* __restrict__ x16out, int wr16,
    const int* __restrict__ seg,     // CSR offsets (N+1)
    const int2* __restrict__ pe,     // (src, w)
    const float* __restrict__ affine /* [128]: scale|shift of input */,
    const float* __restrict__ W1T, const float* __restrict__ b1,
    const float* __restrict__ W2T, const float* __restrict__ b2,
    float* __restrict__ out /* xs base + layer*64, row stride OUTD */,
    float* __restrict__ pstat /* [NLBLK][128]: sum|sumsq partials */) {
    __shared__ float lds[NPB * LDS_PITCH];
    int t = threadIdx.x;
    int lane = t & 63;
    int wid = __builtin_amdgcn_readfirstlane(t >> 6);   // wave id 0..3, SGPR
    int nbase = blockIdx.x * NPB;

    int slot = lane >> 4;            // 0..3: which edge of a 4-group
    int col  = lane & 15;            // which float4 of the row
    const float4* aff4 = (const float4*)affine;
    float4 sc4 = aff4[col];          // scale for cols 4c..4c+3
    float4 sh4 = aff4[16 + col];     // shift

    // ---- Phase 1: gather (16 nodes per wave, node id wave-uniform) ----
    for (int nn = 0; nn < 16; ++nn) {
        int nl = wid * 16 + nn;
        int n = nbase + nl;
        float ax = 0.f, ay = 0.f, az = 0.f, aw = 0.f, wsa = 0.f;
        float bx = 0.f, by = 0.f, bz = 0.f, bw = 0.f, wsb = 0.f;
        if (n < N_NODES) {
            int beg = seg[n];
            int end = seg[n + 1];
#define GBODY(EI, X, Y, Z, W, WS)                                              \
            if ((EI) < end) {                                                  \
                int2 p = pe[EI];                                               \
                float w = __int_as_float(p.y);                                 \
                float vx, vy, vz, vw;                                          \
                if (BF16IN) {                                                  \
                    ushort4 hv =                                               \
                        ((const ushort4*)(x16in + (size_t)p.x * DIM))[col];    \
                    vx = bf2f(hv.x); vy = bf2f(hv.y);                          \
                    vz = bf2f(hv.z); vw = bf2f(hv.w);                          \
                } else {                                                       \
                    float4 fv =                                                \
                        ((const float4*)(x_in + (size_t)p.x * xstride))[col];  \
                    vx = fv.x; vy = fv.y; vz = fv.z; vw = fv.w;                \
                }                                                              \
                X = fmaf(w, vx, X); Y = fmaf(w, vy, Y);                        \
                Z = fmaf(w, vz, Z); W = fmaf(w, vw, W);                        \
                WS += w;                                                       \
            }
            for (int e = beg; e < end; e += 16) {
                int e0 = e + slot;
                GBODY(e0,      ax, ay, az, aw, wsa)
                GBODY(e0 + 4,  bx, by, bz, bw, wsb)
                GBODY(e0 + 8,  ax, ay, az, aw, wsa)
                GBODY(e0 + 12, bx, by, bz, bw, wsb)
            }
#undef GBODY
        }
        float sx = ax + bx, sy = ay + by, sz = az + bz, sw = aw + bw;
        float ws = wsa + wsb;
        // reduce across the 4 slots (lane bits 4,5); all lanes get totals
        sx += __shfl_xor(sx, 16); sy += __shfl_xor(sy, 16);
        sz += __shfl_xor(sz, 16); sw += __shfl_xor(sw, 16);
        ws += __shfl_xor(ws, 16);
        sx += __shfl_xor(sx, 32); sy += __shfl_xor(sy, 32);
        sz += __shfl_xor(sz, 32); sw += __shfl_xor(sw, 32);
        ws += __shfl_xor(ws, 32);
        if (lane < 16) {
            float r0 = 0.f, r1 = 0.f, r2 = 0.f, r3 = 0.f;
            if (n < N_NODES) {
                const float4* xr =
                    (const float4*)(x_in + (size_t)n * xstride) + col;
                float4 s = *xr;                       // self term, f32
                float shw = 1.0f + ws;
                r0 = fmaf(sc4.x, sx + s.x, sh4.x * shw);
                r1 = fmaf(sc4.y, sy + s.y, sh4.y * shw);
                r2 = fmaf(sc4.z, sz + s.z, sh4.z * shw);
                r3 = fmaf(sc4.w, sw + s.w, sh4.w * shw);
            }
            int lb = nl * LDS_PITCH + col * 4;
            lds[lb] = r0; lds[lb + 1] = r1; lds[lb + 2] = r2; lds[lb + 3] = r3;
        }
    }
    __syncthreads();

    // ---- Stage 1 GEMM: hidden = relu(xin @ W1^T + b1) ----
    float h[16];
#pragma unroll
    for (int jj = 0; jj < 16; ++jj) h[jj] = b1[wid * 16 + jj];
#pragma unroll 4
    for (int k = 0; k < DIM; ++k) {
        float xv = lds[lane * LDS_PITCH + k];
        const float* wr = W1T + k * DIM + wid * 16;   // uniform -> s_load
#pragma unroll
        for (int jj = 0; jj < 16; ++jj) h[jj] = fmaf(xv, wr[jj], h[jj]);
    }
#pragma unroll
    for (int jj = 0; jj < 16; ++jj) h[jj] = fmaxf(h[jj], 0.0f);
    __syncthreads();          // all lds (xin) reads done
#pragma unroll
    for (int jj = 0; jj < 16; ++jj) lds[lane * LDS_PITCH + wid * 16 + jj] = h[jj];
    __syncthreads();

    // ---- Stage 2 GEMM: o = relu(hidden @ W2^T + b2) ----
    float o[16];
#pragma unroll
    for (int jj = 0; jj < 16; ++jj) o[jj] = b2[wid * 16 + jj];
#pragma unroll 4
    for (int k = 0; k < DIM; ++k) {
        float hv = lds[lane * LDS_PITCH + k];
        const float* wr = W2T + k * DIM + wid * 16;
#pragma unroll
        for (int jj = 0; jj < 16; ++jj) o[jj] = fmaf(hv, wr[jj], o[jj]);
    }
    int n = nbase + lane;
    bool valid = (n < N_NODES);
#pragma unroll
    for (int jj = 0; jj < 16; ++jj) o[jj] = fmaxf(o[jj], 0.0f);
    if (valid) {
        float* orow = out + (size_t)n * OUTD + wid * 16;
#pragma unroll
        for (int jj = 0; jj < 16; jj += 4) {
            *(float4*)(orow + jj) = make_float4(o[jj], o[jj + 1], o[jj + 2], o[jj + 3]);
        }
        if (wr16) {
            unsigned short* hrow = x16out + (size_t)n * DIM + wid * 16;
#pragma unroll
            for (int jj = 0; jj < 16; jj += 4) {
                ushort4 hq;
                hq.x = f2bf(o[jj]);     hq.y = f2bf(o[jj + 1]);
                hq.z = f2bf(o[jj + 2]); hq.w = f2bf(o[jj + 3]);
                *(ushort4*)(hrow + jj) = hq;
            }
        }
    }

    // ---- BN stat partials: butterfly over 64 lanes; wave wid owns dims
    // [wid*16, wid*16+16). Non-atomic coalesced per-block store.
    float my_s = 0.0f, my_q = 0.0f;
#pragma unroll
    for (int jj = 0; jj < 16; ++jj) {
        float v = valid ? o[jj] : 0.0f;
        float vs = v, vq = v * v;
#pragma unroll
        for (int m = 1; m < 64; m <<= 1) {
            vs += __shfl_xor(vs, m);
            vq += __shfl_xor(vq, m);
        }
        if (lane == jj) { my_s = vs; my_q = vq; }
    }
    if (lane < 16) {
        size_t base = (size_t)blockIdx.x * 128 + wid * 16 + lane;
        pstat[base] = my_s;
        pstat[base + 64] = my_q;
    }
}

// ---------------------------------------------------------------------------
// Reduce per-block BN partials -> scale/shift; optionally zero pooled
// (folds the pooled memset's dispatch into the last reduce).
__global__ void __launch_bounds__(256) reduce_stats(
    const float* __restrict__ pstat,
    const float* __restrict__ gamma, const float* __restrict__ beta,
    float* __restrict__ ss /* [128]: scale|shift */,
    float* __restrict__ pooled, int zpool) {
    __shared__ double part[16][16];
    int b = blockIdx.x;            // 0..7
    int t = threadIdx.x;
    if (zpool) {
        for (int i = b * 256 + t; i < N_GRAPHS * OUTD; i += 8 * 256)
            pooled[i] = 0.0f;
    }
    int slot = t & 15;             // 0..7 -> sum(d), 8..15 -> sumsq(d)
    int g = t >> 4;                // group 0..15
    int d = b * 8 + (slot & 7);
    int off = (slot < 8) ? 0 : 64;
    double s = 0.0;
    for (int blk = g; blk < NLBLK; blk += 16)
        s += (double)pstat[(size_t)blk * 128 + off + d];
    part[g][slot] = s;
    __syncthreads();
    if (t < 16) {
        double x = 0.0;
#pragma unroll
        for (int k = 0; k < 16; ++k) x += part[k][t];
        part[0][t] = x;            // column t only -> no hazard
    }
    __syncthreads();
    if (t < 8) {
        int dd = b * 8 + t;
        double mu = part[0][t] / (double)N_NODES;
        double var = part[0][8 + t] / (double)N_NODES - mu * mu;
        float inv = (float)(1.0 / sqrt(var + (double)BN_EPS));
        float sc = gamma[dd] * inv;
        ss[dd] = sc;
        ss[64 + dd] = beta[dd] - (float)mu * sc;
    }
}

// ---------------------------------------------------------------------------
// Final pass: apply BN affine to xs IN PLACE (all 3 layers at once) and
// add-pool per graph. Grid (512 graphs, 4 parts), block 192.
__global__ void bn_pool(float* __restrict__ xs,
                        const int* __restrict__ batch,
                        const float* __restrict__ ss /* [3][128] */,
                        float* __restrict__ pooled) {
    int g = blockIdx.x;
    int part = blockIdx.y;   // 0..3
    int d = threadIdx.x;     // 0..191
    int l = d >> 6, dd = d & 63;
    float sc = ss[l * 128 + dd];
    float sh = ss[l * 128 + 64 + dd];
    int start, end;
    {
        int lo = 0, hi = N_NODES;
        while (lo < hi) { int m = (lo + hi) >> 1; if (batch[m] < g) lo = m + 1; else hi = m; }
        start = lo;
    }
    {
        int lo = start, hi = N_NODES;
        while (lo < hi) { int m = (lo + hi) >> 1; if (batch[m] <= g) lo = m + 1; else hi = m; }
        end = lo;
    }
    float acc = 0.0f;
    for (int n = start + part; n < end; n += 4) {
        float* p = xs + (size_t)n * OUTD + d;
        float v = fmaf(*p, sc, sh);
        *p = v;
        acc += v;
    }
    atomicAdd(&pooled[(size_t)g * OUTD + d], acc);
}

// ---------------------------------------------------------------------------
extern "C" void kernel_launch(void* const* d_in, const int* in_sizes, int n_in,
                              void* d_out, int out_size, void* d_ws, size_t ws_size,
                              hipStream_t stream) {
    const float* x0    = (const float*)d_in[0];
    const int*   ei    = (const int*)d_in[1];
    const float* ew    = (const float*)d_in[2];
    const int*   batch = (const int*)d_in[3];
    const float* W1    = (const float*)d_in[5];
    const float* b1    = (const float*)d_in[6];
    const float* W2    = (const float*)d_in[7];
    const float* b2    = (const float*)d_in[8];
    const float* gamma = (const float*)d_in[9];
    const float* beta  = (const float*)d_in[10];

    float* pooled = (float*)d_out;                      // [512, 192]
    float* xs     = pooled + (size_t)N_GRAPHS * OUTD;   // [100000, 192]

    const int* src = ei;
    const int* dst = ei + N_EDGES;

    // Workspace (~36.6 MB): head = persistent; tail union = {binning scratch}
    // overlapped with {x16 ping-pong} (pp/hist/pbase dead before layer 0
    // writes x16; layer 0 reads f32 so needs no x16 input).
    int2*  pe     = (int2*)d_ws;                        // E  9.6 MB
    int*   seg    = (int*)(pe + N_EDGES);               // N+4
    int*   tot    = seg + N_NODES + 4;                  // NBUK+4
    float* W1T    = (float*)(tot + NBUK + 4);
    float* W2T    = W1T + N_LAYERS * DIM * DIM;
    float* idaff  = W2T + N_LAYERS * DIM * DIM;         // 128 floats
    float* ss     = idaff + 128;                        // 3*128 floats
    float* pstat  = ss + N_LAYERS * 128;                // NLBLK*128 floats
    // union region:
    char* uni = (char*)(pstat + (size_t)NLBLK * 128);
    int2*  pp     = (int2*)uni;                         // E (binning only)
    int*   hist   = (int*)(pp + N_EDGES);               // NPBLK*NBUK
    int*   pbase  = hist + (size_t)NPBLK * NBUK;        // NPBLK*NBUK
    unsigned short* x16a = (unsigned short*)uni;        // N*64 bf16 (12.8 MB)
    unsigned short* x16b = x16a + (size_t)N_NODES * DIM;

    transpose_w<<<(N_LAYERS * DIM * DIM + 255) / 256, 256, 0, stream>>>(
        W1, W2, W1T, W2T, idaff, tot);

    // Two-level binning (4 dispatches; scan196/memsets folded away).
    part_hist<<<NPBLK, 256, 0, stream>>>(dst, hist, tot);
    base_fill<<<NBUK, 256, 0, stream>>>(hist, tot, pbase);
    part_scatter<<<NPBLK, 256, 0, stream>>>(src, dst, ew, pbase, pp);
    csr_build<<<NBUK, 256, 0, stream>>>(pp, tot, seg, pe);

    for (int i = 0; i < N_LAYERS; ++i) {
        const float* xin = (i == 0) ? x0 : (xs + (size_t)(i - 1) * DIM);
        int xstride = (i == 0) ? DIM : OUTD;
        const float* affine = (i == 0) ? idaff : (ss + (size_t)(i - 1) * 128);
        const unsigned short* x16in = (i == 1) ? x16b : x16a;
        unsigned short* x16out = (i == 0) ? x16b : x16a;
        int wr16 = (i < N_LAYERS - 1) ? 1 : 0;

        if (i == 0) {
            layer_kernel<0><<<NLBLK, 256, 0, stream>>>(
                xin, xstride, x16in, x16out, wr16, seg, pe, affine,
                W1T + (size_t)i * DIM * DIM, b1 + (size_t)i * DIM,
                W2T + (size_t)i * DIM * DIM, b2 + (size_t)i * DIM,
                xs + (size_t)i * DIM, pstat);
        } else {
            layer_kernel<1><<<NLBLK, 256, 0, stream>>>(
                xin, xstride, x16in, x16out, wr16, seg, pe, affine,
                W1T + (size_t)i * DIM * DIM, b1 + (size_t)i * DIM,
                W2T + (size_t)i * DIM * DIM, b2 + (size_t)i * DIM,
                xs + (size_t)i * DIM, pstat);
        }

        reduce_stats<<<8, 256, 0, stream>>>(
            pstat, gamma + (size_t)i * DIM, beta + (size_t)i * DIM,
            ss + (size_t)i * 128, pooled, (i == N_LAYERS - 1) ? 1 : 0);
    }

    dim3 pgrid(N_GRAPHS, 4);
    bn_pool<<<pgrid, OUTD, 0, stream>>>(xs, batch, ss, pooled);
}